// Round 2
// baseline (375.352 us; speedup 1.0000x reference)
//
#include <hip/hip_runtime.h>
#include <hip/hip_bf16.h>

// Problem: B=8, N=1024, D=768, H=12, dh=64. I/O is FP32 (per reference); internal
// compute bf16 MFMA (threshold = 2% of max|ref| permits it).
// Pipeline: [0] convert x,Wq,Wk,Wv,Wo fp32->bf16 into ws
//           [1] QKV gemm (x @ W^T) -> q,k,v [B,H,N,64] bf16 in ws
//           [2] flash attention per (b,h,128-row q chunk) -> attn [B*N,768] bf16 in ws
//           [3] out gemm (attn @ Wo^T + bo) -> d_out fp32
// MFMA 16x16x32 bf16. A/B frag: elem(lane&15 row, quad*8+j k) = 16B row-major load.
// C/D frag: col=lane&15, row=quad*4+r (HW-verified mapping).

typedef unsigned short u16;
typedef __attribute__((ext_vector_type(8))) short bf8;   // 8 bf16 in 4 VGPRs
typedef __attribute__((ext_vector_type(4))) float f4;
typedef __attribute__((ext_vector_type(4))) unsigned short us4;

#define NB 8
#define NSEQ 1024
#define DMODEL 768
#define NHEAD 12
#define DHEAD 64

#define XELEMS   (NB * NSEQ * DMODEL)          // 6291456
#define WELEMS   (DMODEL * DMODEL)             // 589824 (each of Wq/Wk/Wv/Wo)

__device__ __forceinline__ float b2f(u16 u) {
  union { unsigned int i; float f; } c; c.i = ((unsigned int)u) << 16; return c.f;
}
__device__ __forceinline__ u16 f2b(float f) {
  union { float f; unsigned int i; } c; c.f = f;
  unsigned int r = c.i + 0x7fffu + ((c.i >> 16) & 1u);
  return (u16)(r >> 16);
}

// ---------------- Stage 0: fp32 -> bf16 conversion ----------------
struct CvtArgs {
  const float* src[5];
  u16* dst[5];
};
#define G0 (XELEMS / 4)   // 1572864 float4 groups for x
#define GW (WELEMS / 4)   // 147456 groups per weight
#define GTOT (G0 + 4 * GW)

__global__ __launch_bounds__(256) void cvt_kernel(CvtArgs a) {
  size_t g = (size_t)blockIdx.x * 256 + threadIdx.x;
  if (g >= GTOT) return;
  int t; size_t off;
  if (g < G0) { t = 0; off = g; }
  else { size_t r = g - G0; t = 1 + (int)(r / GW); off = r % GW; }
  f4 v = *(const f4*)(a.src[t] + off * 4);
  us4 o;
  o[0] = f2b(v[0]); o[1] = f2b(v[1]); o[2] = f2b(v[2]); o[3] = f2b(v[3]);
  *(us4*)(a.dst[t] + off * 4) = o;
}

// ---------------- Stage 1: QKV projection ----------------
// C[m, n] = sum_k x[m,k] * W[n,k];  n in [0,2304) = proj*768 + h*64 + e
// grid (64, 18), 256 thr. Block tile 128x128, wave tile 64x64.
__global__ __launch_bounds__(256) void qkv_gemm(
    const u16* __restrict__ x, const u16* __restrict__ Wq,
    const u16* __restrict__ Wk, const u16* __restrict__ Wv,
    u16* __restrict__ q, u16* __restrict__ k, u16* __restrict__ v)
{
  const int tid  = threadIdx.x;
  const int lane = tid & 63;
  const int w    = tid >> 6;
  const int wm   = w >> 1, wn = w & 1;
  const int col  = lane & 15;
  const int quad = lane >> 4;
  const int bm = blockIdx.x;   // 0..63
  const int bn = blockIdx.y;   // 0..17

  const int m0 = bm * 128 + wm * 64;
  const int proj = bn / 6;                      // 0=q,1=k,2=v
  const u16* Wsel = (proj == 0) ? Wq : (proj == 1 ? Wk : Wv);
  const int nrem0 = (bn % 6) * 128 + wn * 64;   // col within this proj's 768

  f4 acc[4][4];
#pragma unroll
  for (int i = 0; i < 4; i++)
#pragma unroll
    for (int j = 0; j < 4; j++) acc[i][j] = (f4)0.0f;

  for (int kk = 0; kk < DMODEL; kk += 32) {
    const int kr = kk + quad * 8;
    bf8 af[4], bfr[4];
#pragma unroll
    for (int mt = 0; mt < 4; mt++) {
      const int row = m0 + mt * 16 + col;
      af[mt] = *(const bf8*)(x + (size_t)row * DMODEL + kr);
    }
#pragma unroll
    for (int nt = 0; nt < 4; nt++) {
      const int nr = nrem0 + nt * 16 + col;
      bfr[nt] = *(const bf8*)(Wsel + (size_t)nr * DMODEL + kr);
    }
#pragma unroll
    for (int mt = 0; mt < 4; mt++)
#pragma unroll
      for (int nt = 0; nt < 4; nt++)
        acc[mt][nt] = __builtin_amdgcn_mfma_f32_16x16x32_bf16(af[mt], bfr[nt], acc[mt][nt], 0, 0, 0);
  }

  u16* dst = (proj == 0) ? q : (proj == 1 ? k : v);
#pragma unroll
  for (int mt = 0; mt < 4; mt++) {
#pragma unroll
    for (int nt = 0; nt < 4; nt++) {
      const int nc = nrem0 + nt * 16 + col;
      const int h = nc >> 6, e = nc & 63;
#pragma unroll
      for (int r = 0; r < 4; r++) {
        const int t = m0 + mt * 16 + quad * 4 + r;      // global token row
        const int b = t >> 10, tok = t & 1023;
        dst[((size_t)(b * NHEAD + h) * NSEQ + tok) * DHEAD + e] = f2b(acc[mt][nt][r]);
      }
    }
  }
}

// ---------------- Stage 2: flash attention ----------------
// grid (8 qchunks, 12 heads, 8 batch), 256 thr = 4 waves x 32 q-rows.
__global__ __launch_bounds__(256) void attn_kernel(
    const u16* __restrict__ q, const u16* __restrict__ k,
    const u16* __restrict__ v, u16* __restrict__ attn)
{
  __shared__ __align__(16) u16 ldsVT[DHEAD][136];     // V tile transposed, padded
  __shared__ __align__(16) u16 ldsP[4][32][136];      // per-wave P (C-layout -> A-layout)

  const int tid  = threadIdx.x;
  const int lane = tid & 63;
  const int w    = tid >> 6;
  const int col  = lane & 15;
  const int quad = lane >> 4;
  const int qc = blockIdx.x, h = blockIdx.y, b = blockIdx.z;
  const size_t head = ((size_t)b * NHEAD + h) * NSEQ * DHEAD;
  const int q0 = qc * 128 + w * 32;

  // Q fragments, pre-scaled by 1/sqrt(64)=0.125 (exact in bf16)
  bf8 qf[2][2];
#pragma unroll
  for (int mt = 0; mt < 2; mt++)
#pragma unroll
    for (int kt = 0; kt < 2; kt++) {
      const int row = q0 + mt * 16 + col;
      bf8 t = *(const bf8*)(q + head + (size_t)row * DHEAD + kt * 32 + quad * 8);
#pragma unroll
      for (int j = 0; j < 8; j++) t[j] = (short)f2b(b2f((u16)t[j]) * 0.125f);
      qf[mt][kt] = t;
    }

  float m_[2][4], l_[2][4];
  f4 o[2][4];
#pragma unroll
  for (int mt = 0; mt < 2; mt++) {
#pragma unroll
    for (int r = 0; r < 4; r++) { m_[mt][r] = -1e30f; l_[mt][r] = 0.0f; }
#pragma unroll
    for (int et = 0; et < 4; et++) o[mt][et] = (f4)0.0f;
  }

  for (int t = 0; t < NSEQ / 128; t++) {
    const int kbase = t * 128;
    __syncthreads();   // previous iteration's VT reads done
    // stage V tile transposed into LDS
#pragma unroll
    for (int it = 0; it < 4; it++) {
      const int chunk = it * 256 + tid;      // 0..1023
      const int row = chunk >> 3;            // 0..127
      const int c8 = (chunk & 7) * 8;
      bf8 tv = *(const bf8*)(v + head + (size_t)(kbase + row) * DHEAD + c8);
#pragma unroll
      for (int j = 0; j < 8; j++) ldsVT[c8 + j][row] = (u16)tv[j];
    }
    __syncthreads();

    // S = (Q/8) @ K^T   [32 x 128] per wave
    f4 s[2][8];
#pragma unroll
    for (int mt = 0; mt < 2; mt++)
#pragma unroll
      for (int nt = 0; nt < 8; nt++) s[mt][nt] = (f4)0.0f;
#pragma unroll
    for (int kt = 0; kt < 2; kt++) {
      bf8 kf[8];
#pragma unroll
      for (int nt = 0; nt < 8; nt++) {
        const int row = kbase + nt * 16 + col;
        kf[nt] = *(const bf8*)(k + head + (size_t)row * DHEAD + kt * 32 + quad * 8);
      }
#pragma unroll
      for (int mt = 0; mt < 2; mt++)
#pragma unroll
        for (int nt = 0; nt < 8; nt++)
          s[mt][nt] = __builtin_amdgcn_mfma_f32_16x16x32_bf16(qf[mt][kt], kf[nt], s[mt][nt], 0, 0, 0);
    }

    // online softmax update
#pragma unroll
    for (int mt = 0; mt < 2; mt++) {
      float alpha[4];
#pragma unroll
      for (int r = 0; r < 4; r++) {
        float mx = s[mt][0][r];
#pragma unroll
        for (int nt = 1; nt < 8; nt++) mx = fmaxf(mx, s[mt][nt][r]);
        mx = fmaxf(mx, __shfl_xor(mx, 1, 64));
        mx = fmaxf(mx, __shfl_xor(mx, 2, 64));
        mx = fmaxf(mx, __shfl_xor(mx, 4, 64));
        mx = fmaxf(mx, __shfl_xor(mx, 8, 64));
        const float mn = fmaxf(m_[mt][r], mx);
        alpha[r] = __expf(m_[mt][r] - mn);
        m_[mt][r] = mn;
      }
      float rs[4] = {0.f, 0.f, 0.f, 0.f};
#pragma unroll
      for (int nt = 0; nt < 8; nt++)
#pragma unroll
        for (int r = 0; r < 4; r++) {
          const float p = __expf(s[mt][nt][r] - m_[mt][r]);
          rs[r] += p;
          ldsP[w][mt * 16 + quad * 4 + r][nt * 16 + col] = f2b(p);
        }
#pragma unroll
      for (int r = 0; r < 4; r++) {
        float sum = rs[r];
        sum += __shfl_xor(sum, 1, 64);
        sum += __shfl_xor(sum, 2, 64);
        sum += __shfl_xor(sum, 4, 64);
        sum += __shfl_xor(sum, 8, 64);
        l_[mt][r] = l_[mt][r] * alpha[r] + sum;
      }
#pragma unroll
      for (int et = 0; et < 4; et++)
#pragma unroll
        for (int r = 0; r < 4; r++) o[mt][et][r] *= alpha[r];
    }

    // O += P @ V  (P A-frags from wave-private LDS; V B-frags from transposed LDS)
#pragma unroll
    for (int kt2 = 0; kt2 < 4; kt2++) {
      bf8 pf[2], vf[4];
#pragma unroll
      for (int mt = 0; mt < 2; mt++)
        pf[mt] = *(const bf8*)&ldsP[w][mt * 16 + col][kt2 * 32 + quad * 8];
#pragma unroll
      for (int et = 0; et < 4; et++)
        vf[et] = *(const bf8*)&ldsVT[et * 16 + col][kt2 * 32 + quad * 8];
#pragma unroll
      for (int mt = 0; mt < 2; mt++)
#pragma unroll
        for (int et = 0; et < 4; et++)
          o[mt][et] = __builtin_amdgcn_mfma_f32_16x16x32_bf16(pf[mt], vf[et], o[mt][et], 0, 0, 0);
    }
  }

  // epilogue: O /= l, write concat-head layout [B*N, 768]
#pragma unroll
  for (int mt = 0; mt < 2; mt++)
#pragma unroll
    for (int r = 0; r < 4; r++) {
      const float inv = 1.0f / l_[mt][r];
      const int token = q0 + mt * 16 + quad * 4 + r;
#pragma unroll
      for (int et = 0; et < 4; et++)
        attn[(size_t)(b * NSEQ + token) * DMODEL + h * DHEAD + et * 16 + col] =
            f2b(o[mt][et][r] * inv);
    }
}

// ---------------- Stage 3: output projection + bias ----------------
// out[m,n] = sum_k attn[m,k] * Wo[n,k] + bo[n];  grid (64, 6). FP32 out.
__global__ __launch_bounds__(256) void out_gemm(
    const u16* __restrict__ attn, const u16* __restrict__ Wo,
    const float* __restrict__ bo, float* __restrict__ out)
{
  const int tid  = threadIdx.x;
  const int lane = tid & 63;
  const int w    = tid >> 6;
  const int wm   = w >> 1, wn = w & 1;
  const int col  = lane & 15;
  const int quad = lane >> 4;
  const int bm = blockIdx.x;   // 0..63
  const int bn = blockIdx.y;   // 0..5

  const int m0 = bm * 128 + wm * 64;
  const int n0 = bn * 128 + wn * 64;

  f4 acc[4][4];
#pragma unroll
  for (int i = 0; i < 4; i++)
#pragma unroll
    for (int j = 0; j < 4; j++) acc[i][j] = (f4)0.0f;

  for (int kk = 0; kk < DMODEL; kk += 32) {
    const int kr = kk + quad * 8;
    bf8 af[4], bfr[4];
#pragma unroll
    for (int mt = 0; mt < 4; mt++) {
      const int row = m0 + mt * 16 + col;
      af[mt] = *(const bf8*)(attn + (size_t)row * DMODEL + kr);
    }
#pragma unroll
    for (int nt = 0; nt < 4; nt++) {
      const int nr = n0 + nt * 16 + col;
      bfr[nt] = *(const bf8*)(Wo + (size_t)nr * DMODEL + kr);
    }
#pragma unroll
    for (int mt = 0; mt < 4; mt++)
#pragma unroll
      for (int nt = 0; nt < 4; nt++)
        acc[mt][nt] = __builtin_amdgcn_mfma_f32_16x16x32_bf16(af[mt], bfr[nt], acc[mt][nt], 0, 0, 0);
  }

#pragma unroll
  for (int mt = 0; mt < 4; mt++)
#pragma unroll
    for (int nt = 0; nt < 4; nt++) {
      const int n = n0 + nt * 16 + col;
      const float bias = bo[n];
#pragma unroll
      for (int r = 0; r < 4; r++) {
        const int row = m0 + mt * 16 + quad * 4 + r;
        out[(size_t)row * DMODEL + n] = acc[mt][nt][r] + bias;
      }
    }
}

extern "C" void kernel_launch(void* const* d_in, const int* in_sizes, int n_in,
                              void* d_out, int out_size, void* d_ws, size_t ws_size,
                              hipStream_t stream) {
  const float* x  = (const float*)d_in[0];
  const float* Wq = (const float*)d_in[1];
  const float* Wk = (const float*)d_in[2];
  const float* Wv = (const float*)d_in[3];
  const float* Wo = (const float*)d_in[4];
  const float* bo = (const float*)d_in[5];
  float* out = (float*)d_out;

  // ws layout (u16 elems): xb | wqb | wkb | wvb | wob | q | k | v | attn
  u16* xb   = (u16*)d_ws;
  u16* wqb  = xb  + XELEMS;
  u16* wkb  = wqb + WELEMS;
  u16* wvb  = wkb + WELEMS;
  u16* wob  = wvb + WELEMS;
  u16* q    = wob + WELEMS;
  u16* k    = q   + XELEMS;
  u16* v    = k   + XELEMS;
  u16* attn = v   + XELEMS;

  CvtArgs ca;
  ca.src[0] = x;  ca.src[1] = Wq;  ca.src[2] = Wk;  ca.src[3] = Wv;  ca.src[4] = Wo;
  ca.dst[0] = xb; ca.dst[1] = wqb; ca.dst[2] = wkb; ca.dst[3] = wvb; ca.dst[4] = wob;

  cvt_kernel<<<dim3((GTOT + 255) / 256), 256, 0, stream>>>(ca);
  qkv_gemm<<<dim3(64, 18), 256, 0, stream>>>(xb, wqb, wkb, wvb, q, k, v);
  attn_kernel<<<dim3(8, NHEAD, NB), 256, 0, stream>>>(q, k, v, attn);
  out_gemm<<<dim3(64, 6), 256, 0, stream>>>(attn, wob, bo, out);
}

// Round 3
// 267.730 us; speedup vs baseline: 1.4020x; 1.4020x over previous
//
#include <hip/hip_runtime.h>
#include <hip/hip_bf16.h>

// Problem: B=8, N=1024, D=768, H=12, dh=64. I/O FP32; internal compute bf16 MFMA.
// Pipeline: [0] cvt x,Wq,Wk,Wv,Wo fp32->bf16 into ws
//           [1] QKV gemm (m97-style LDS-staged, global_load_lds w=16) -> q,k,v [B,H,N,64]
//           [2] flash attention per (b,h,128-row q chunk) -> attn [B*N,768] bf16
//           [3] out gemm (same structure) + bias -> d_out fp32
// MFMA 16x16x32 bf16. A/B frag: elem(lane&15 row, quad*8+j k). C/D: col=lane&15, row=quad*4+r.

typedef unsigned short u16;
typedef __attribute__((ext_vector_type(8))) short bf8;   // 8 bf16 in 4 VGPRs
typedef __attribute__((ext_vector_type(4))) float f4;
typedef __attribute__((ext_vector_type(4))) unsigned short us4;

#define NB 8
#define NSEQ 1024
#define DMODEL 768
#define NHEAD 12
#define DHEAD 64

#define XELEMS   (NB * NSEQ * DMODEL)          // 6291456
#define WELEMS   (DMODEL * DMODEL)             // 589824

__device__ __forceinline__ float b2f(u16 u) {
  union { unsigned int i; float f; } c; c.i = ((unsigned int)u) << 16; return c.f;
}
__device__ __forceinline__ u16 f2b(float f) {
  union { float f; unsigned int i; } c; c.f = f;
  unsigned int r = c.i + 0x7fffu + ((c.i >> 16) & 1u);
  return (u16)(r >> 16);
}
// async global->LDS, 16B per lane; l must be the WAVE-UNIFORM base (HW adds lane*16)
__device__ __forceinline__ void gl_lds16(const u16* g, u16* l) {
  __builtin_amdgcn_global_load_lds(
      (const __attribute__((address_space(1))) unsigned int*)g,
      (__attribute__((address_space(3))) unsigned int*)l, 16, 0, 0);
}

// ---------------- Stage 0: fp32 -> bf16 conversion ----------------
struct CvtArgs {
  const float* src[5];
  u16* dst[5];
};
#define G0 (XELEMS / 4)
#define GW (WELEMS / 4)
#define GTOT (G0 + 4 * GW)

__global__ __launch_bounds__(256) void cvt_kernel(CvtArgs a) {
  size_t g = (size_t)blockIdx.x * 256 + threadIdx.x;
  if (g >= GTOT) return;
  int t; size_t off;
  if (g < G0) { t = 0; off = g; }
  else { size_t r = g - G0; t = 1 + (int)(r / GW); off = r % GW; }
  f4 v = *(const f4*)(a.src[t] + off * 4);
  us4 o;
  o[0] = f2b(v[0]); o[1] = f2b(v[1]); o[2] = f2b(v[2]); o[3] = f2b(v[3]);
  *(us4*)(a.dst[t] + off * 4) = o;
}

// ---------------- Stage 1: QKV projection (LDS-staged) ----------------
// C[m,n] = sum_k x[m,k]*W[n,k]; grid (64,18), 256 thr, block tile 128x128, BK=32.
__global__ __launch_bounds__(256) void qkv_gemm(
    const u16* __restrict__ x, const u16* __restrict__ Wq,
    const u16* __restrict__ Wk, const u16* __restrict__ Wv,
    u16* __restrict__ q, u16* __restrict__ k, u16* __restrict__ v)
{
  __shared__ __align__(16) u16 lA[128 * 32];
  __shared__ __align__(16) u16 lB[128 * 32];

  const int tid  = threadIdx.x;
  const int lane = tid & 63;
  const int w    = tid >> 6;
  const int wm   = w >> 1, wn = w & 1;
  const int col  = lane & 15;
  const int quad = lane >> 4;
  const int bm = blockIdx.x;   // 0..63
  const int bn = blockIdx.y;   // 0..17

  const int m0 = bm * 128;
  const int proj = bn / 6;                      // 0=q,1=k,2=v
  const u16* Wsel = (proj == 0) ? Wq : (proj == 1 ? Wk : Wv);
  const int nrem0 = (bn % 6) * 128;

  // staging: wave w covers rows [w*32, w*32+32) in two 16-row loads
  const int srow = lane >> 2;          // 0..15
  const int scol = (lane & 3) * 8;     // 0,8,16,24
  const u16* gA0 = x    + (size_t)(m0    + w * 32 + srow) * DMODEL + scol;
  const u16* gB0 = Wsel + (size_t)(nrem0 + w * 32 + srow) * DMODEL + scol;
  u16* lA0 = lA + w * 1024;            // (w*32 rows)*32 elems
  u16* lB0 = lB + w * 1024;

  f4 acc[4][4];
#pragma unroll
  for (int i = 0; i < 4; i++)
#pragma unroll
    for (int j = 0; j < 4; j++) acc[i][j] = (f4)0.0f;

  for (int kk = 0; kk < DMODEL; kk += 32) {
    __syncthreads();                   // previous frag reads done
    gl_lds16(gA0 + kk, lA0);
    gl_lds16(gA0 + 16 * DMODEL + kk, lA0 + 512);
    gl_lds16(gB0 + kk, lB0);
    gl_lds16(gB0 + 16 * DMODEL + kk, lB0 + 512);
    __syncthreads();                   // drains vmcnt before barrier

    bf8 af[4], bfr[4];
#pragma unroll
    for (int mt = 0; mt < 4; mt++)
      af[mt] = *(const bf8*)&lA[(wm * 64 + mt * 16 + col) * 32 + quad * 8];
#pragma unroll
    for (int nt = 0; nt < 4; nt++)
      bfr[nt] = *(const bf8*)&lB[(wn * 64 + nt * 16 + col) * 32 + quad * 8];
#pragma unroll
    for (int mt = 0; mt < 4; mt++)
#pragma unroll
      for (int nt = 0; nt < 4; nt++)
        acc[mt][nt] = __builtin_amdgcn_mfma_f32_16x16x32_bf16(af[mt], bfr[nt], acc[mt][nt], 0, 0, 0);
  }

  u16* dst = (proj == 0) ? q : (proj == 1 ? k : v);
  const int mw0 = m0 + wm * 64, nw0 = nrem0 + wn * 64;
#pragma unroll
  for (int mt = 0; mt < 4; mt++) {
#pragma unroll
    for (int nt = 0; nt < 4; nt++) {
      const int nc = nw0 + nt * 16 + col;
      const int h = nc >> 6, e = nc & 63;
#pragma unroll
      for (int r = 0; r < 4; r++) {
        const int t = mw0 + mt * 16 + quad * 4 + r;
        const int b = t >> 10, tok = t & 1023;
        dst[((size_t)(b * NHEAD + h) * NSEQ + tok) * DHEAD + e] = f2b(acc[mt][nt][r]);
      }
    }
  }
}

// ---------------- Stage 2: flash attention ----------------
// grid (8 qchunks, 12 heads, 8 batch), 256 thr = 4 waves x 32 q-rows.
__global__ __launch_bounds__(256) void attn_kernel(
    const u16* __restrict__ q, const u16* __restrict__ k,
    const u16* __restrict__ v, u16* __restrict__ attn)
{
  __shared__ __align__(16) u16 ldsVT[DHEAD][136];     // V tile transposed, padded
  __shared__ __align__(16) u16 ldsP[4][32][136];      // per-wave P (C-layout -> A-layout)

  const int tid  = threadIdx.x;
  const int lane = tid & 63;
  const int w    = tid >> 6;
  const int col  = lane & 15;
  const int quad = lane >> 4;
  const int qc = blockIdx.x, h = blockIdx.y, b = blockIdx.z;
  const size_t head = ((size_t)b * NHEAD + h) * NSEQ * DHEAD;
  const int q0 = qc * 128 + w * 32;

  bf8 qf[2][2];
#pragma unroll
  for (int mt = 0; mt < 2; mt++)
#pragma unroll
    for (int kt = 0; kt < 2; kt++) {
      const int row = q0 + mt * 16 + col;
      bf8 t = *(const bf8*)(q + head + (size_t)row * DHEAD + kt * 32 + quad * 8);
#pragma unroll
      for (int j = 0; j < 8; j++) t[j] = (short)f2b(b2f((u16)t[j]) * 0.125f);
      qf[mt][kt] = t;
    }

  float m_[2][4], l_[2][4];
  f4 o[2][4];
#pragma unroll
  for (int mt = 0; mt < 2; mt++) {
#pragma unroll
    for (int r = 0; r < 4; r++) { m_[mt][r] = -1e30f; l_[mt][r] = 0.0f; }
#pragma unroll
    for (int et = 0; et < 4; et++) o[mt][et] = (f4)0.0f;
  }

  for (int t = 0; t < NSEQ / 128; t++) {
    const int kbase = t * 128;
    __syncthreads();
#pragma unroll
    for (int it = 0; it < 4; it++) {
      const int chunk = it * 256 + tid;
      const int row = chunk >> 3;
      const int c8 = (chunk & 7) * 8;
      bf8 tv = *(const bf8*)(v + head + (size_t)(kbase + row) * DHEAD + c8);
#pragma unroll
      for (int j = 0; j < 8; j++) ldsVT[c8 + j][row] = (u16)tv[j];
    }
    __syncthreads();

    f4 s[2][8];
#pragma unroll
    for (int mt = 0; mt < 2; mt++)
#pragma unroll
      for (int nt = 0; nt < 8; nt++) s[mt][nt] = (f4)0.0f;
#pragma unroll
    for (int kt = 0; kt < 2; kt++) {
      bf8 kf[8];
#pragma unroll
      for (int nt = 0; nt < 8; nt++) {
        const int row = kbase + nt * 16 + col;
        kf[nt] = *(const bf8*)(k + head + (size_t)row * DHEAD + kt * 32 + quad * 8);
      }
#pragma unroll
      for (int mt = 0; mt < 2; mt++)
#pragma unroll
        for (int nt = 0; nt < 8; nt++)
          s[mt][nt] = __builtin_amdgcn_mfma_f32_16x16x32_bf16(qf[mt][kt], kf[nt], s[mt][nt], 0, 0, 0);
    }

#pragma unroll
    for (int mt = 0; mt < 2; mt++) {
      float alpha[4];
#pragma unroll
      for (int r = 0; r < 4; r++) {
        float mx = s[mt][0][r];
#pragma unroll
        for (int nt = 1; nt < 8; nt++) mx = fmaxf(mx, s[mt][nt][r]);
        mx = fmaxf(mx, __shfl_xor(mx, 1, 64));
        mx = fmaxf(mx, __shfl_xor(mx, 2, 64));
        mx = fmaxf(mx, __shfl_xor(mx, 4, 64));
        mx = fmaxf(mx, __shfl_xor(mx, 8, 64));
        const float mn = fmaxf(m_[mt][r], mx);
        alpha[r] = __expf(m_[mt][r] - mn);
        m_[mt][r] = mn;
      }
      float rs[4] = {0.f, 0.f, 0.f, 0.f};
#pragma unroll
      for (int nt = 0; nt < 8; nt++)
#pragma unroll
        for (int r = 0; r < 4; r++) {
          const float p = __expf(s[mt][nt][r] - m_[mt][r]);
          rs[r] += p;
          ldsP[w][mt * 16 + quad * 4 + r][nt * 16 + col] = f2b(p);
        }
#pragma unroll
      for (int r = 0; r < 4; r++) {
        float sum = rs[r];
        sum += __shfl_xor(sum, 1, 64);
        sum += __shfl_xor(sum, 2, 64);
        sum += __shfl_xor(sum, 4, 64);
        sum += __shfl_xor(sum, 8, 64);
        l_[mt][r] = l_[mt][r] * alpha[r] + sum;
      }
#pragma unroll
      for (int et = 0; et < 4; et++)
#pragma unroll
        for (int r = 0; r < 4; r++) o[mt][et][r] *= alpha[r];
    }

#pragma unroll
    for (int kt2 = 0; kt2 < 4; kt2++) {
      bf8 pf[2], vf[4];
#pragma unroll
      for (int mt = 0; mt < 2; mt++)
        pf[mt] = *(const bf8*)&ldsP[w][mt * 16 + col][kt2 * 32 + quad * 8];
#pragma unroll
      for (int et = 0; et < 4; et++)
        vf[et] = *(const bf8*)&ldsVT[et * 16 + col][kt2 * 32 + quad * 8];
#pragma unroll
      for (int mt = 0; mt < 2; mt++)
#pragma unroll
        for (int et = 0; et < 4; et++)
          o[mt][et] = __builtin_amdgcn_mfma_f32_16x16x32_bf16(pf[mt], vf[et], o[mt][et], 0, 0, 0);
    }
  }

#pragma unroll
  for (int mt = 0; mt < 2; mt++)
#pragma unroll
    for (int r = 0; r < 4; r++) {
      const float inv = 1.0f / l_[mt][r];
      const int token = q0 + mt * 16 + quad * 4 + r;
#pragma unroll
      for (int et = 0; et < 4; et++)
        attn[(size_t)(b * NSEQ + token) * DMODEL + h * DHEAD + et * 16 + col] =
            f2b(o[mt][et][r] * inv);
    }
}

// ---------------- Stage 3: output projection + bias (LDS-staged) ----------------
// out[m,n] = sum_k attn[m,k]*Wo[n,k] + bo[n]; grid (64,6). FP32 out.
__global__ __launch_bounds__(256) void out_gemm(
    const u16* __restrict__ attn, const u16* __restrict__ Wo,
    const float* __restrict__ bo, float* __restrict__ out)
{
  __shared__ __align__(16) u16 lA[128 * 32];
  __shared__ __align__(16) u16 lB[128 * 32];

  const int tid  = threadIdx.x;
  const int lane = tid & 63;
  const int w    = tid >> 6;
  const int wm   = w >> 1, wn = w & 1;
  const int col  = lane & 15;
  const int quad = lane >> 4;
  const int bm = blockIdx.x;   // 0..63
  const int bn = blockIdx.y;   // 0..5

  const int m0 = bm * 128;
  const int n0 = bn * 128;

  const int srow = lane >> 2;
  const int scol = (lane & 3) * 8;
  const u16* gA0 = attn + (size_t)(m0 + w * 32 + srow) * DMODEL + scol;
  const u16* gB0 = Wo   + (size_t)(n0 + w * 32 + srow) * DMODEL + scol;
  u16* lA0 = lA + w * 1024;
  u16* lB0 = lB + w * 1024;

  f4 acc[4][4];
#pragma unroll
  for (int i = 0; i < 4; i++)
#pragma unroll
    for (int j = 0; j < 4; j++) acc[i][j] = (f4)0.0f;

  for (int kk = 0; kk < DMODEL; kk += 32) {
    __syncthreads();
    gl_lds16(gA0 + kk, lA0);
    gl_lds16(gA0 + 16 * DMODEL + kk, lA0 + 512);
    gl_lds16(gB0 + kk, lB0);
    gl_lds16(gB0 + 16 * DMODEL + kk, lB0 + 512);
    __syncthreads();

    bf8 af[4], bfr[4];
#pragma unroll
    for (int mt = 0; mt < 4; mt++)
      af[mt] = *(const bf8*)&lA[(wm * 64 + mt * 16 + col) * 32 + quad * 8];
#pragma unroll
    for (int nt = 0; nt < 4; nt++)
      bfr[nt] = *(const bf8*)&lB[(wn * 64 + nt * 16 + col) * 32 + quad * 8];
#pragma unroll
    for (int mt = 0; mt < 4; mt++)
#pragma unroll
      for (int nt = 0; nt < 4; nt++)
        acc[mt][nt] = __builtin_amdgcn_mfma_f32_16x16x32_bf16(af[mt], bfr[nt], acc[mt][nt], 0, 0, 0);
  }

  const int mw0 = m0 + wm * 64, nw0 = n0 + wn * 64;
#pragma unroll
  for (int mt = 0; mt < 4; mt++)
#pragma unroll
    for (int nt = 0; nt < 4; nt++) {
      const int n = nw0 + nt * 16 + col;
      const float bias = bo[n];
#pragma unroll
      for (int r = 0; r < 4; r++) {
        const int row = mw0 + mt * 16 + quad * 4 + r;
        out[(size_t)row * DMODEL + n] = acc[mt][nt][r] + bias;
      }
    }
}

extern "C" void kernel_launch(void* const* d_in, const int* in_sizes, int n_in,
                              void* d_out, int out_size, void* d_ws, size_t ws_size,
                              hipStream_t stream) {
  const float* x  = (const float*)d_in[0];
  const float* Wq = (const float*)d_in[1];
  const float* Wk = (const float*)d_in[2];
  const float* Wv = (const float*)d_in[3];
  const float* Wo = (const float*)d_in[4];
  const float* bo = (const float*)d_in[5];
  float* out = (float*)d_out;

  u16* xb   = (u16*)d_ws;
  u16* wqb  = xb  + XELEMS;
  u16* wkb  = wqb + WELEMS;
  u16* wvb  = wkb + WELEMS;
  u16* wob  = wvb + WELEMS;
  u16* q    = wob + WELEMS;
  u16* k    = q   + XELEMS;
  u16* v    = k   + XELEMS;
  u16* attn = v   + XELEMS;

  CvtArgs ca;
  ca.src[0] = x;  ca.src[1] = Wq;  ca.src[2] = Wk;  ca.src[3] = Wv;  ca.src[4] = Wo;
  ca.dst[0] = xb; ca.dst[1] = wqb; ca.dst[2] = wkb; ca.dst[3] = wvb; ca.dst[4] = wob;

  cvt_kernel<<<dim3((GTOT + 255) / 256), 256, 0, stream>>>(ca);
  qkv_gemm<<<dim3(64, 18), 256, 0, stream>>>(xb, wqb, wkb, wvb, q, k, v);
  attn_kernel<<<dim3(8, NHEAD, NB), 256, 0, stream>>>(q, k, v, attn);
  out_gemm<<<dim3(64, 6), 256, 0, stream>>>(attn, wob, bo, out);
}